// Round 7
// baseline (653.433 us; speedup 1.0000x reference)
//
#include <hip/hip_runtime.h>
#include <hip/hip_bf16.h>
#include <math.h>

#define NTOK 8192
#define DIM  768
#define HDIM 3072
#define NE   8
#define CAP  2560
#define AMAX 16384

typedef __bf16 bf16x8  __attribute__((ext_vector_type(8)));
typedef __bf16 bf16x2  __attribute__((ext_vector_type(2)));
typedef float  floatx4 __attribute__((ext_vector_type(4)));

typedef unsigned int u32_g __attribute__((address_space(1)));
typedef unsigned int u32_l __attribute__((address_space(3)));

__device__ __forceinline__ void gl_lds16(const void* g, void* l) {
  // 16B per lane, LDS dest = wave-uniform base + lane*16
  __builtin_amdgcn_global_load_lds((const u32_g*)g, (u32_l*)l, 16, 0, 0);
}

// gelu exact via A&S 7.1.26 erf poly (|err| < 1.5e-7)
__device__ __forceinline__ float gelu_exact(float v) {
  float z = fabsf(v) * 0.7071067811865475f;
  float t = __builtin_amdgcn_rcpf(1.0f + 0.3275911f * z);
  float p = ((((1.061405429f * t - 1.453152027f) * t + 1.421413741f) * t
              - 0.284496736f) * t + 0.254829592f) * t;
  float e = 1.0f - p * __expf(-z * z);
  e = copysignf(e, v);
  return 0.5f * v * (1.0f + e);
}

// ---------------- fused weight transpose + fp32->bf16: [E][K][N] -> [E][N][K] ----------
__global__ __launch_bounds__(256) void transpose_conv2(
    const float* __restrict__ w1, const float* __restrict__ w2,
    __bf16* __restrict__ o1, __bf16* __restrict__ o2)
{
  const int which = blockIdx.z;
  const float* src = which ? w2 : w1;
  __bf16* dst = which ? o2 : o1;
  const int Kd = which ? HDIM : DIM;
  const int Nd = which ? DIM : HDIM;
  const int e = blockIdx.y;
  const int tilesK = Kd >> 6;
  const int bk = blockIdx.x % tilesK, bn = blockIdx.x / tilesK;
  __shared__ float T[64][65];
  const float* se = src + (size_t)e * Kd * Nd;
  const int k0 = bk * 64, n0 = bn * 64;
  const int tid = threadIdx.x;
  // float4 global loads (G13): 64x64 f32 tile = 1024 float4, 4 per thread
#pragma unroll
  for (int it = 0; it < 4; ++it) {
    int flat4 = tid + it * 256;
    int kk = flat4 >> 4, c4 = flat4 & 15;
    float4 v = *(const float4*)(se + (size_t)(k0 + kk) * Nd + n0 + c4 * 4);
    T[kk][c4 * 4 + 0] = v.x; T[kk][c4 * 4 + 1] = v.y;
    T[kk][c4 * 4 + 2] = v.z; T[kk][c4 * 4 + 3] = v.w;
  }
  __syncthreads();
  const int n = tid >> 2, kg = tid & 3;
  bf16x8 v0, v1;
#pragma unroll
  for (int q = 0; q < 8; ++q) v0[q] = (__bf16)T[kg * 16 + q][n];
#pragma unroll
  for (int q = 0; q < 8; ++q) v1[q] = (__bf16)T[kg * 16 + 8 + q][n];
  __bf16* de = dst + (size_t)e * Nd * Kd + (size_t)(n0 + n) * Kd + k0 + kg * 16;
  *(bf16x8*)(de) = v0;
  *(bf16x8*)(de + 8) = v1;
}

// ---------------- router: block-aggregated dispatch (1 global atomic per expert/block) --
__global__ __launch_bounds__(256) void router_kernel(
    const float* __restrict__ x, const float* __restrict__ rw,
    int* __restrict__ list_len, double* __restrict__ imp, double* __restrict__ loadacc,
    int* __restrict__ aidx, float* __restrict__ keyarr, float* __restrict__ warr)
{
  __shared__ float Wl[NE * DIM];
  __shared__ int   lcount[NE], lbase[NE];
  __shared__ int   s_e[32][2], s_pos[32][2];
  __shared__ float s_key[32][2], s_w[32][2];
  const int tid = threadIdx.x;
  for (int i = tid; i < NE * DIM; i += 256) {
    int e = i / DIM, d = i - e * DIM;
    Wl[i] = rw[d * NE + e];
  }
  if (tid < NE) lcount[tid] = 0;
  __syncthreads();
  const int wave = tid >> 6, lane = tid & 63;
  double my_imp = 0.0, my_load = 0.0;

  for (int it = 0; it < 8; ++it) {
    const int t = wave * 8 + it;               // block-local token
    const int n = blockIdx.x * 32 + t;
    const float* xr = x + (size_t)n * DIM;
    float part[NE];
#pragma unroll
    for (int e = 0; e < NE; ++e) part[e] = 0.f;
#pragma unroll
    for (int c = 0; c < DIM / 64; ++c) {
      float xv = xr[c * 64 + lane];
#pragma unroll
      for (int e = 0; e < NE; ++e) part[e] += xv * Wl[e * DIM + c * 64 + lane];
    }
#pragma unroll
    for (int off = 32; off > 0; off >>= 1) {
#pragma unroll
      for (int e = 0; e < NE; ++e) part[e] += __shfl_xor(part[e], off);
    }
    // top-2, ties -> lower index (lax.top_k semantics)
    int e0 = 0; float v0 = part[0];
#pragma unroll
    for (int e = 1; e < NE; ++e) if (part[e] > v0) { v0 = part[e]; e0 = e; }
    int e1 = -1; float v1 = -3.4e38f;
#pragma unroll
    for (int e = 0; e < NE; ++e) if (e != e0 && part[e] > v1) { v1 = part[e]; e1 = e; }

    float pexp[NE]; float s = 0.f;
#pragma unroll
    for (int e = 0; e < NE; ++e) { pexp[e] = expf(part[e] - v0); s += pexp[e]; }
    const float inv = 1.0f / s;
    const float pr = inv;               // top-1 prob = priority
    float w1v = 0.f;
#pragma unroll
    for (int e = 0; e < NE; ++e) if (e == e1) w1v = pexp[e] * inv;

    // per-lane-expert double accumulation: lane e accumulates expert e
    float myl = 0.f, mypexp = 0.f;
#pragma unroll
    for (int e = 0; e < NE; ++e) if (lane == e) { myl = part[e]; mypexp = pexp[e]; }
    if (lane < NE) {
      my_imp  += (double)(mypexp * inv);
      // 1 - Phi((thr - logit)/NOISE_STD) = 0.5*erfc((thr-logit)/(0.125*sqrt(2)))
      my_load += (double)(0.5f * erfcf((v1 - myl) * 5.656854249492380f));
    }
    if (lane == 0) {
      int p0 = atomicAdd(&lcount[e0], 1);      // LDS atomic (cheap)
      int p1 = atomicAdd(&lcount[e1], 1);
      s_e[t][0] = e0; s_pos[t][0] = p0;
      s_key[t][0] = (float)(e0 * 4) - pr;      // e*(K+2) - score, fp32 like ref
      s_w[t][0] = pr;
      s_e[t][1] = e1; s_pos[t][1] = p1;
      s_key[t][1] = (float)(e1 * 4) - (pr - 1.0f);
      s_w[t][1] = w1v;
    }
  }
  __syncthreads();
  if (tid < NE) lbase[tid] = atomicAdd(&list_len[tid], lcount[tid]);  // 8 global atomics/block
  __syncthreads();
  if (tid < 64) {
    const int t = tid >> 1, sl = tid & 1;
    const int e = s_e[t][sl];
    const int gp = lbase[e] + s_pos[t][sl];
    const int n = blockIdx.x * 32 + t;
    aidx[e * AMAX + gp]   = n * 2 + sl;
    keyarr[e * AMAX + gp] = s_key[t][sl];
    warr[e * AMAX + gp]   = s_w[t][sl];
  }
  if (lane < NE) {
    unsafeAtomicAdd(&imp[lane], my_imp);
    unsafeAtomicAdd(&loadacc[lane], my_load);
  }
}

// ---------------- capacity keep/compact + scalar outputs -------------------------------
__global__ __launch_bounds__(256) void compact_kernel(
    const int* __restrict__ list_len, const int* __restrict__ aidx,
    const float* __restrict__ keyarr, const float* __restrict__ warr,
    int* __restrict__ dtok, float* __restrict__ dw,
    const double* __restrict__ imp, const double* __restrict__ loadacc,
    float* __restrict__ out_scalars)
{
  __shared__ float sk[6144];
  __shared__ int   sa[6144];
  const int e = blockIdx.x, tid = threadIdx.x;
  const int C = list_len[e];
  if (C <= CAP) {
    for (int t = tid; t < C; t += 256) {
      int a = aidx[e * AMAX + t];
      dtok[e * CAP + t] = a >> 1;
      dw[e * CAP + t]   = warr[e * AMAX + t];
    }
  } else {
    const bool useL = (C <= 6144);
    if (useL) {
      for (int t = tid; t < C; t += 256) { sk[t] = keyarr[e*AMAX+t]; sa[t] = aidx[e*AMAX+t]; }
      __syncthreads();
    }
    for (int t = tid; t < C; t += 256) {
      float kt = keyarr[e*AMAX+t]; int at = aidx[e*AMAX+t];
      int r = 0;
      for (int u = 0; u < C; ++u) {
        float ku = useL ? sk[u] : keyarr[e*AMAX+u];
        int   au = useL ? sa[u] : aidx[e*AMAX+u];
        if (ku < kt || (ku == kt && au < at)) ++r;
      }
      if (r < CAP) { dtok[e*CAP + r] = at >> 1; dw[e*CAP + r] = warr[e*AMAX+t]; }
    }
  }
  if (e == 0 && tid == 0) {
    double mi = 0, ml = 0;
    for (int i = 0; i < NE; ++i) { mi += imp[i]; ml += loadacc[i]; }
    mi /= NE; ml /= NE;
    double vi = 0, vl = 0;
    for (int i = 0; i < NE; ++i) {
      double di = imp[i] - mi;     vi += di * di;
      double dl = loadacc[i] - ml; vl += dl * dl;
    }
    vi /= NE; vl /= NE;
    double li = vi / (mi * mi + 1e-6), ll = vl / (ml * ml + 1e-6);
    out_scalars[0] = (float)(0.5 * (li + ll));
    int drop = 0;
    for (int i = 0; i < NE; ++i) { int c2 = list_len[i]; if (c2 > CAP) drop += c2 - CAP; }
    out_scalars[1] = (float)drop;
    for (int i = 0; i < NE; ++i) out_scalars[2 + i] = (float)list_len[i];
  }
}

// ---------------- gather kept rows into padded bf16 A buffer [E][CAP][DIM] -------------
__global__ __launch_bounds__(256) void gather_kernel(
    const float* __restrict__ x, const int* __restrict__ dtok,
    const int* __restrict__ list_len, __bf16* __restrict__ Ag)
{
  const int row  = blockIdx.x * 4 + (threadIdx.x >> 6);
  const int lane = threadIdx.x & 63;
  const int e = row / CAP, slot = row - e * CAP;
  const int kept = min(list_len[e], CAP);
  __bf16* dst = Ag + (size_t)row * DIM;
  if (slot < kept) {
    const float* srcr = x + (size_t)dtok[e * CAP + slot] * DIM;
#pragma unroll
    for (int c = 0; c < DIM / 128; ++c) {
      float2 v = *(const float2*)(srcr + c * 128 + lane * 2);
      bf16x2 o; o[0] = (__bf16)v.x; o[1] = (__bf16)v.y;
      *(bf16x2*)(dst + c * 128 + lane * 2) = o;
    }
  } else {
    bf16x2 z; z[0] = (__bf16)0.f; z[1] = (__bf16)0.f;
#pragma unroll
    for (int c = 0; c < DIM / 128; ++c) *(bf16x2*)(dst + c * 128 + lane * 2) = z;
  }
}

// ---------------- grouped GEMM: m97 structure. 128x128 tile, 4 waves, BK=32, ----------
// single 16KB LDS buffer, plain __syncthreads, 3 blocks/CU co-resident.
// Rationale: 5 rounds of 256-tile/8-wave/1-block-per-CU schedules (2-phase, 8-phase,
// deep-vmcnt, sched_barrier, persistent) ALL plateaued at MfmaUtil 17-21% -- with one
// block per CU every barrier stalls the whole CU. m97 (874-912 TF verified on this
// MFMA shape, plain HIP) instead relies on INTER-BLOCK overlap: small blocks, small
// LDS, 3 blocks/CU; while one block sits at its staging barrier another issues MFMA.
// Per K-step: sync; 4x gl_lds (A 8KB + B 8KB, fragment-ordered 512-elem chunks,
// lane-linear -> linear gl_lds dest AND 0-conflict ds_read_b128); sync; 8x ds_read;
// 16 MFMA. No inline waitcnt/setprio/sched_barrier -- compiler-scheduled (m97-style).
// Wave (wm,wn) owns 64x64 quadrant: acc[4][4], C/D: col=lane&15, row=(lane>>4)*4+reg.
// e = bid&7 -> xcd (weights L2-resident per XCD); tm-inner q enum -> co-resident
// blocks share the B tn-panel (L2 hit) while walking A rows.
template<int MODE>
__global__ __launch_bounds__(256, 3) void moe_gemm97(
    const __bf16* __restrict__ Aall, const __bf16* __restrict__ BTall,
    const float* __restrict__ bias, __bf16* __restrict__ Hout,
    float* __restrict__ Out, const int* __restrict__ dtok, const float* __restrict__ dww,
    const int* __restrict__ list_len)
{
  const int Kd = MODE ? HDIM : DIM;
  const int Nd = MODE ? DIM : HDIM;
  const int nT = Kd / 32;             // 24 (FC1) / 96 (FC2)
  const int TM = CAP / 128;           // 20

  const int e = blockIdx.x & 7;       // xcd-pinned expert
  const int q = blockIdx.x >> 3;
  const int tm = q % TM, tn = q / TM;

  const int kept = min(list_len[e], CAP);
  if (tm >= ((kept + 127) >> 7)) return;

  __shared__ __align__(16) __bf16 S[8192];   // A 4096 + B 4096 elems = 16 KB

  const int tid = threadIdx.x, lane = tid & 63, wave = tid >> 6;  // 4 waves
  const int wm = wave & 1, wn = wave >> 1;
  const int m0 = tm * 128, n0 = tn * 128;
  const int lr = lane & 15, kq = lane >> 4;

  const __bf16* Abase = Aall + (size_t)e * CAP * Kd;
  const __bf16* Bbase = BTall + (size_t)e * Nd * Kd;
  const __bf16* gA0 = Abase + (size_t)(m0 + (wave * 2 + 0) * 16 + lr) * Kd + kq * 8;
  const __bf16* gA1 = Abase + (size_t)(m0 + (wave * 2 + 1) * 16 + lr) * Kd + kq * 8;
  const __bf16* gB0 = Bbase + (size_t)(n0 + (wave * 2 + 0) * 16 + lr) * Kd + kq * 8;
  const __bf16* gB1 = Bbase + (size_t)(n0 + (wave * 2 + 1) * 16 + lr) * Kd + kq * 8;

  floatx4 acc[4][4];
#pragma unroll
  for (int i = 0; i < 4; ++i)
#pragma unroll
    for (int j = 0; j < 4; ++j) acc[i][j] = (floatx4)0.f;

  bf16x8 aR[4], bR[4];

#pragma unroll 1
  for (int t = 0; t < nT; ++t) {
    __syncthreads();                       // prev tile's LDS reads retired
    gl_lds16(gA0 + t * 32, &S[(wave * 2 + 0) * 512]);
    gl_lds16(gA1 + t * 32, &S[(wave * 2 + 1) * 512]);
    gl_lds16(gB0 + t * 32, &S[4096 + (wave * 2 + 0) * 512]);
    gl_lds16(gB1 + t * 32, &S[4096 + (wave * 2 + 1) * 512]);
    __syncthreads();                       // staged data visible (compiler drains vmcnt)
#pragma unroll
    for (int m = 0; m < 4; ++m)
      aR[m] = *(const bf16x8*)&S[(wm * 4 + m) * 512 + lane * 8];
#pragma unroll
    for (int n = 0; n < 4; ++n)
      bR[n] = *(const bf16x8*)&S[4096 + (wn * 4 + n) * 512 + lane * 8];
#pragma unroll
    for (int m = 0; m < 4; ++m)
#pragma unroll
      for (int n = 0; n < 4; ++n)
        acc[m][n] = __builtin_amdgcn_mfma_f32_16x16x32_bf16(aR[m], bR[n], acc[m][n], 0, 0, 0);
  }

  // ---- epilogue ---- C/D layout: col=lane&15, row=(lane>>4)*4+reg
  const int quad = lane >> 4, lcol = lane & 15;
  float bcol[4];
#pragma unroll
  for (int n = 0; n < 4; ++n)
    bcol[n] = bias[e * Nd + n0 + wn * 64 + n * 16 + lcol];

  if (MODE == 0) {
#pragma unroll
    for (int m = 0; m < 4; ++m) {
#pragma unroll
      for (int r = 0; r < 4; ++r) {
        const int row = m0 + wm * 64 + m * 16 + quad * 4 + r;
        __bf16* hrow = Hout + ((size_t)(e * CAP + row)) * Nd + n0 + wn * 64;
#pragma unroll
        for (int n = 0; n < 4; ++n)
          hrow[n * 16 + lcol] = (__bf16)gelu_exact(acc[m][n][r] + bcol[n]);
      }
    }
  } else {
#pragma unroll
    for (int m = 0; m < 4; ++m) {
#pragma unroll
      for (int r = 0; r < 4; ++r) {
        const int row = m0 + wm * 64 + m * 16 + quad * 4 + r;
        const float w = dww[e * CAP + row];
        if (w != 0.0f) {
          const int tok = dtok[e * CAP + row];
          float* orow = Out + (size_t)tok * DIM + n0 + wn * 64;
#pragma unroll
          for (int n = 0; n < 4; ++n)
            unsafeAtomicAdd(&orow[n * 16 + lcol], w * (acc[m][n][r] + bcol[n]));
        }
      }
    }
  }
}

extern "C" void kernel_launch(void* const* d_in, const int* in_sizes, int n_in,
                              void* d_out, int out_size, void* d_ws, size_t ws_size,
                              hipStream_t stream) {
  (void)in_sizes; (void)n_in; (void)out_size; (void)ws_size;
  const float* x  = (const float*)d_in[0];
  const float* rw = (const float*)d_in[1];
  const float* w1 = (const float*)d_in[2];
  const float* b1 = (const float*)d_in[3];
  const float* w2 = (const float*)d_in[4];
  const float* b2 = (const float*)d_in[5];
  float* out = (float*)d_out;
  char* ws = (char*)d_ws;

  int*    list_len = (int*)(ws + 0);
  double* imp      = (double*)(ws + 64);
  double* loadacc  = (double*)(ws + 128);
  int*    dtok     = (int*)(ws + 256);
  float*  dw       = (float*)(ws + 256 + 81920);
  int*    aidx     = (int*)(ws + 164096);
  float*  keyarr   = (float*)(ws + 164096 + 524288);
  float*  warr     = (float*)(ws + 164096 + 1048576);
  __bf16* W1T      = (__bf16*)(ws + 2097152);
  __bf16* W2T      = (__bf16*)(ws + 2097152 + 37748736);
  __bf16* Ag       = (__bf16*)(ws + 2097152 + 2 * 37748736);
  __bf16* hbuf     = (__bf16*)(ws + 2097152 + 2 * 37748736 + 31457280);

  hipMemsetAsync(d_out, 0, (size_t)NTOK * DIM * sizeof(float), stream);
  hipMemsetAsync(ws, 0, 164096, stream);

  transpose_conv2<<<dim3(576, 8, 2), 256, 0, stream>>>(w1, w2, W1T, W2T);
  router_kernel<<<NTOK / 32, 256, 0, stream>>>(x, rw, list_len, imp, loadacc, aidx, keyarr, warr);
  compact_kernel<<<NE, 256, 0, stream>>>(list_len, aidx, keyarr, warr, dtok, dw, imp, loadacc,
                                         out + (size_t)NTOK * DIM);
  gather_kernel<<<(NE * CAP) / 4, 256, 0, stream>>>(x, dtok, list_len, Ag);
  // FC1: 8 xcd x (20 tm x 24 tn) = 3840 blocks, 256 thr, 16KB LDS, 3 blocks/CU
  moe_gemm97<0><<<NE * (CAP / 128) * (HDIM / 128), 256, 0, stream>>>(
      Ag, W1T, b1, hbuf, nullptr, nullptr, nullptr, list_len);
  // FC2: 8 xcd x (20 tm x 6 tn) = 960 blocks
  moe_gemm97<1><<<NE * (CAP / 128) * (DIM / 128), 256, 0, stream>>>(
      hbuf, W2T, b2, nullptr, out, dtok, dw, list_len);
}